// Round 10
// baseline (401.563 us; speedup 1.0000x reference)
//
#include <hip/hip_runtime.h>
#include <hip/hip_bf16.h>

// Grouped GEMM: out[n,g,k] = sum_d x[n*8+g, d] * W[g, k, d]
// Round 10: m97-replica adapted to fp32 inputs.
//  - 128x128 tile, BK=64, 4 waves (2x2), 256 threads, 3 blocks/CU.
//  - LDS 48 KiB: A single-buffer 16 KiB (bf16), B double-buffer 32 KiB.
//  - A: reg-staged from raw X f32 (8 f32x4 loads at tile top, 8 cvt_pk +
//    4 ds_write_b128 at tile bottom -> full-tile in-flight window).
//  - B: bf16 image in d_ws (cvt_w pre-pass, ~8us, XCD-L2-resident), staged
//    via 4 glds16/thread/tile with pre-swizzled-image involution (both-sides).
//  - Two barriers/tile; one VM0 with full-compute window; cross-block TLP
//    (3 blocks/CU) hides drains (m114/m97 mechanism).

namespace {

constexpr int NG   = 8;
constexpr int DIN  = 1024;
constexpr int DOUT = 1024;
constexpr int BM   = 128;
constexpr int BN   = 128;
constexpr int BK   = 64;
constexpr int NKT  = DIN / BK;            // 16
constexpr int ROWB = BK * 2;              // 128 B per LDS row (64 bf16)
constexpr int TILE = BM * ROWB;           // 16 KiB
constexpr int JTN  = DOUT / BN;           // 8 col panels
constexpr size_t WSB_BYTES = (size_t)NG * JTN * NKT * TILE;  // 16.78 MB

typedef __attribute__((ext_vector_type(8))) short bf16x8;
typedef __attribute__((ext_vector_type(4))) float f32x4;

__device__ __forceinline__ bf16x8 pack_bf16x8v(f32x4 lo, f32x4 hi) {
  union { __hip_bfloat162 h2[4]; bf16x8 v; } p;
  p.h2[0] = __float22bfloat162_rn(make_float2(lo.x, lo.y));
  p.h2[1] = __float22bfloat162_rn(make_float2(lo.z, lo.w));
  p.h2[2] = __float22bfloat162_rn(make_float2(hi.x, hi.y));
  p.h2[3] = __float22bfloat162_rn(make_float2(hi.z, hi.w));
  return p.v;
}

__device__ __forceinline__ void glds16(const void* g, void* l) {
  __builtin_amdgcn_global_load_lds(
      (const __attribute__((address_space(1))) unsigned int*)g,
      (__attribute__((address_space(3))) unsigned int*)l, 16, 0, 0);
}

#define FENCE() asm volatile("" ::: "memory")
#define BAR()   do { FENCE(); __builtin_amdgcn_s_barrier(); FENCE(); } while (0)
#define LGKM0() asm volatile("s_waitcnt lgkmcnt(0)" ::: "memory")
#define VM0()   asm volatile("s_waitcnt vmcnt(0)" ::: "memory")
#define MFMA_(a, b, c) __builtin_amdgcn_mfma_f32_16x16x32_bf16((a), (b), (c), 0, 0, 0)

// ---------------- cvt_w: W f32 -> bf16 swizzled B-image --------------------
// tiles (g, jt:8, kt:16) of [128 rows][8 granules x 16 B]. Image granule p of
// row r holds SOURCE k-chunk (p ^ (r&7)) -> linear glds dest == swizzled tile.
__global__ __launch_bounds__(256)
void cvt_w_kernel(const float* __restrict__ W, char* __restrict__ wsB) {
  const int q    = (int)blockIdx.x * 256 + (int)threadIdx.x;  // granule id
  const int tile = q >> 10;            // (g*8+jt)*16+kt; 1024 granules/tile
  const int r    = (q & 1023) >> 3;    // row 0..127
  const int p    = q & 7;              // phys granule in row
  const int g    = tile >> 7;
  const int jt   = (tile >> 4) & 7;
  const int kt   = tile & 15;

  const int l = p ^ (r & 7);           // logical (source) granule
  const float* src = W + (size_t)(g * DOUT + jt * BN + r) * DIN + kt * BK + l * 8;
  f32x4 lo = *(const f32x4*)(src);
  f32x4 hi = *(const f32x4*)(src + 4);
  *(bf16x8*)(wsB + (size_t)q * 16) = pack_bf16x8v(lo, hi);
}

// ---------------- gemm ------------------------------------------------------
template <bool WSB>
__global__ __launch_bounds__(256, 3)
void gemm_k(const float* __restrict__ X, const float* __restrict__ W,
            const char* __restrict__ wsB, float* __restrict__ O) {
  __shared__ __align__(16) char smA[TILE];        // 16 KiB, single-buffer
  __shared__ __align__(16) char smB[2 * TILE];    // 32 KiB, double-buffer

  // ---- block mapping: group == XCD (4096 blocks, 512/XCD), bijective
  const int bid = (int)blockIdx.x;
  const int swz = (bid & 7) * 512 + (bid >> 3);
  const int jt = swz & 7;                 // col panel [0,8) fastest (X reuse)
  const int it = (swz >> 3) & 63;         // row tile  [0,64)
  const int g  = swz >> 9;                // group     [0,8)  == XCD

  const int n0 = it * BM;
  const int c0 = jt * BN;

  const int tid  = (int)threadIdx.x;
  const int lane = tid & 63;
  const int wid  = tid >> 6;              // 4 waves: 2(M) x 2(N)
  const int wr   = wid >> 1;
  const int wc   = wid & 1;
  const int fr   = lane & 15;
  const int fq   = lane >> 4;

  // ---- A staging map: row r = tid>>1 (128 rows), half h = tid&1 (k 32-each)
  const int ar = tid >> 1;
  const int ah = tid & 1;
  const float* aSrc = X + ((size_t)(n0 + ar) * NG + g) * DIN + ah * 32;
  // 4 LDS write addresses (involution: phys granule = (h*4+j) ^ (r&7))
  int awb[4];
#pragma unroll
  for (int j = 0; j < 4; ++j)
    awb[j] = ar * ROWB + (((ah * 4 + j) ^ (ar & 7)) << 4);

  // ---- B: image stream (WSB) or raw W reg-staged (fallback)
  const char* BgT = wsB + (size_t)((g * JTN + jt) * NKT) * TILE;
  const float* bSrc = W + (size_t)(g * DOUT + c0 + ar) * DIN + ah * 32;

  // ---- fragment LDS addressing (same involution both operands)
  int acol[2], arow_[4], brow_[4];
#pragma unroll
  for (int ks = 0; ks < 2; ++ks)
    acol[ks] = ((ks * 4 + fq) ^ (fr & 7)) << 4;
#pragma unroll
  for (int m = 0; m < 4; ++m) {
    arow_[m] = (wr * 64 + m * 16 + fr) * ROWB;
    brow_[m] = (wc * 64 + m * 16 + fr) * ROWB;
  }

  f32x4 aS[8], bS[8];
  f32x4 acc[4][4];
#pragma unroll
  for (int m = 0; m < 4; ++m)
#pragma unroll
    for (int n = 0; n < 4; ++n) acc[m][n] = (f32x4){0.f, 0.f, 0.f, 0.f};

  // ---- prologue: stage tile 0
  if (WSB) {
#pragma unroll
    for (int k = 0; k < 4; ++k)
      glds16(BgT + tid * 16 + k * 4096, smB + tid * 16 + k * 4096);
  } else {
#pragma unroll
    for (int c = 0; c < 8; ++c) bS[c] = *(const f32x4*)(bSrc + c * 4);
  }
#pragma unroll
  for (int c = 0; c < 8; ++c) aS[c] = *(const f32x4*)(aSrc + c * 4);
#pragma unroll
  for (int j = 0; j < 4; ++j)
    *(bf16x8*)(smA + awb[j]) = pack_bf16x8v(aS[2 * j], aS[2 * j + 1]);
  if (!WSB) {
#pragma unroll
    for (int j = 0; j < 4; ++j)
      *(bf16x8*)(smB + awb[j]) = pack_bf16x8v(bS[2 * j], bS[2 * j + 1]);
  }
  LGKM0();
  if (WSB) { VM0(); }
  BAR();

#pragma unroll 2
  for (int t = 0; t < NKT; ++t) {
    const bool st = (t + 1) < NKT;
    char* const bb = smB + (WSB ? (t & 1) * TILE : 0);
    char* const bn = smB + (WSB ? ((t & 1) ^ 1) * TILE : 0);

    // ---- tile top: issue next-tile loads (full-tile in-flight window)
    if (st) {
      if (WSB) {
        const char* Bn = BgT + (size_t)(t + 1) * TILE;
#pragma unroll
        for (int k = 0; k < 4; ++k)
          glds16(Bn + tid * 16 + k * 4096, bn + tid * 16 + k * 4096);
      }
      const float* An = aSrc + (size_t)(t + 1) * BK;
#pragma unroll
      for (int c = 0; c < 8; ++c) aS[c] = *(const f32x4*)(An + c * 4);
      if (!WSB) {
        const float* Bn = bSrc + (size_t)(t + 1) * BK;
#pragma unroll
        for (int c = 0; c < 8; ++c) bS[c] = *(const f32x4*)(Bn + c * 4);
      }
    }

    // ---- compute: 2 k-subtiles, 16 MFMA each
#pragma unroll
    for (int ks = 0; ks < 2; ++ks) {
      bf16x8 af[4], bf[4];
#pragma unroll
      for (int m = 0; m < 4; ++m) {
        af[m] = *(const bf16x8*)(smA + arow_[m] + acol[ks]);
        bf[m] = *(const bf16x8*)(bb + brow_[m] + acol[ks]);
      }
      __builtin_amdgcn_s_setprio(1);
#pragma unroll
      for (int m = 0; m < 4; ++m)
#pragma unroll
        for (int n = 0; n < 4; ++n)
          acc[m][n] = MFMA_(af[m], bf[n], acc[m][n]);
      __builtin_amdgcn_s_setprio(0);
    }

    BAR();   // all waves done reading smA (and bb)

    // ---- tile bottom: cvt+write A(t+1) in place; publish
    if (st) {
#pragma unroll
      for (int j = 0; j < 4; ++j)
        *(bf16x8*)(smA + awb[j]) = pack_bf16x8v(aS[2 * j], aS[2 * j + 1]);
      if (!WSB) {
#pragma unroll
        for (int j = 0; j < 4; ++j)
          *(bf16x8*)(smB + awb[j]) = pack_bf16x8v(bS[2 * j], bS[2 * j + 1]);
      }
      LGKM0();
      if (WSB) { VM0(); }   // B(t+1) DMA landed (issued a full tile ago)
      BAR();
    }
  }

  // ---- epilogue: C/D layout col = lane&15, row = (lane>>4)*4 + reg (m89)
#pragma unroll
  for (int m = 0; m < 4; ++m) {
#pragma unroll
    for (int r = 0; r < 4; ++r) {
      const int row = wr * 64 + m * 16 + fq * 4 + r;
      float* orow = O + ((size_t)(n0 + row) * NG + g) * DOUT + c0 + wc * 64;
#pragma unroll
      for (int n = 0; n < 4; ++n) {
        orow[n * 16 + fr] = acc[m][n][r];
      }
    }
  }
}

} // namespace

extern "C" void kernel_launch(void* const* d_in, const int* in_sizes, int n_in,
                              void* d_out, int out_size, void* d_ws, size_t ws_size,
                              hipStream_t stream) {
  (void)n_in; (void)out_size;
  const float* X = (const float*)d_in[0];
  const float* W = (const float*)d_in[1];
  float* O = (float*)d_out;

  const int tokens_total = in_sizes[0] / DIN;            // 65536
  const int ntok_per_g   = tokens_total / NG;            // 8192
  const int grid = NG * (ntok_per_g / BM) * (DOUT / BN); // 4096

  if (ws_size >= WSB_BYTES) {
    const int cvt_grid = (int)(WSB_BYTES / 16 / 256);    // 4096
    cvt_w_kernel<<<dim3(cvt_grid), dim3(256), 0, stream>>>(W, (char*)d_ws);
    gemm_k<true><<<dim3(grid), dim3(256), 0, stream>>>(
        X, W, (const char*)d_ws, O);
  } else {
    gemm_k<false><<<dim3(grid), dim3(256), 0, stream>>>(
        X, W, nullptr, O);
  }
}

// Round 11
// 223.745 us; speedup vs baseline: 1.7947x; 1.7947x over previous
//
#include <hip/hip_runtime.h>
#include <hip/hip_bf16.h>

// Grouped GEMM: out[n,g,k] = sum_d x[n*8+g, d] * W[g, k, d]
// Round 11: producer/consumer WAVE SPECIALIZATION, single kernel, no ws.
//  - 256x256 tile, BK=64, 12 waves: wid 0-7 consumers (2Mx4N, 128x64/wave,
//    acc 8x4), wid 8-11 producers (all staging: f32 loads + cvt_pk +
//    ds_write bf16). Staging runs CONCURRENT with MFMA on other waves.
//  - LDS 128 KiB: A dbuf 2x32 KiB + B dbuf 2x32 KiB, granule^(row&7)
//    involution swizzle (conflict-free, verified R6/R8).
//  - ONE s_barrier per K-tile (producers fill buf^1 while consumers read buf).
//  - setprio(1) around consumer MFMA (T5: role diversity now exists).
//  - group-per-XCD block swizzle (T1); jt fastest for X L2 reuse.

namespace {

constexpr int NG   = 8;
constexpr int DIN  = 1024;
constexpr int DOUT = 1024;
constexpr int BM   = 256;
constexpr int BN   = 256;
constexpr int BK   = 64;
constexpr int NKT  = DIN / BK;            // 16
constexpr int ROWB = BK * 2;              // 128 B per LDS row
constexpr int TILE = BM * ROWB;           // 32 KiB per tile buffer
constexpr int LDS_BYTES = 4 * TILE;       // 128 KiB
constexpr int JTN  = DOUT / BN;           // 4

typedef __attribute__((ext_vector_type(8))) short bf16x8;
typedef __attribute__((ext_vector_type(4))) float f32x4;

__device__ __forceinline__ bf16x8 pack_bf16x8v(f32x4 lo, f32x4 hi) {
  union { __hip_bfloat162 h2[4]; bf16x8 v; } p;
  p.h2[0] = __float22bfloat162_rn(make_float2(lo.x, lo.y));
  p.h2[1] = __float22bfloat162_rn(make_float2(lo.z, lo.w));
  p.h2[2] = __float22bfloat162_rn(make_float2(hi.x, hi.y));
  p.h2[3] = __float22bfloat162_rn(make_float2(hi.z, hi.w));
  return p.v;
}

#define FENCE() asm volatile("" ::: "memory")
#define BAR()   do { FENCE(); __builtin_amdgcn_s_barrier(); FENCE(); } while (0)
#define LGKM0() asm volatile("s_waitcnt lgkmcnt(0)" ::: "memory")
#define MFMA_(a, b, c) __builtin_amdgcn_mfma_f32_16x16x32_bf16((a), (b), (c), 0, 0, 0)

// producers: stage one 256x64 A-tile + 256x64 B-tile (f32 -> bf16, swizzled).
// 256 threads: thread handles rows prow+32j (j=0..7), k-granule pchk (8 bf16).
// Issue all 32 loads first (A then B), then cvt+write (counted vmcnt).
__device__ __forceinline__ void stage_tile(
    const float* __restrict__ aB, const float* __restrict__ bB, int kcol,
    char* __restrict__ nA, char* __restrict__ nB, int pdst0) {
  f32x4 aL[16], bL[16];
#pragma unroll
  for (int j = 0; j < 8; ++j) {
    const float* s = aB + (size_t)j * (32 * NG * DIN) + kcol;
    aL[2 * j]     = *(const f32x4*)(s);
    aL[2 * j + 1] = *(const f32x4*)(s + 4);
  }
#pragma unroll
  for (int j = 0; j < 8; ++j) {
    const float* s = bB + (size_t)j * (32 * DIN) + kcol;
    bL[2 * j]     = *(const f32x4*)(s);
    bL[2 * j + 1] = *(const f32x4*)(s + 4);
  }
#pragma unroll
  for (int j = 0; j < 8; ++j)
    *(bf16x8*)(nA + pdst0 + j * 4096) = pack_bf16x8v(aL[2 * j], aL[2 * j + 1]);
#pragma unroll
  for (int j = 0; j < 8; ++j)
    *(bf16x8*)(nB + pdst0 + j * 4096) = pack_bf16x8v(bL[2 * j], bL[2 * j + 1]);
}

__global__ __launch_bounds__(768)
void gemm_spec(const float* __restrict__ X, const float* __restrict__ W,
               float* __restrict__ O) {
  extern __shared__ char smem[];
  char* const smA = smem;                  // [2][256][64] bf16, swizzled
  char* const smB = smem + 2 * TILE;

  // ---- block mapping: group == XCD (1024 blocks, 128/XCD), bijective
  const int bid = (int)blockIdx.x;
  const int swz = (bid & 7) * 128 + (bid >> 3);
  const int jt = swz & 3;                  // col panel [0,4) fastest (X reuse)
  const int it = (swz >> 2) & 31;          // row tile  [0,32)
  const int g  = swz >> 7;                 // group     [0,8)  == XCD

  const int n0 = it * BM;
  const int c0 = jt * BN;

  const int tid  = (int)threadIdx.x;
  const int lane = tid & 63;
  const int wid  = tid >> 6;               // 0-7 consumers, 8-11 producers

  // ---- producer addressing
  const int ptid = tid - 512;              // 0..255 (valid when wid >= 8)
  const int prow = (ptid & 255) >> 3;      // row base 0..31 (masked for safety)
  const int pchk = ptid & 7;               // logical k-granule
  const float* aB = X + ((size_t)(n0 + prow) * NG + g) * DIN + pchk * 8;
  const float* bB = W + ((size_t)(g * DOUT + c0 + prow)) * DIN + pchk * 8;
  const int pdst0 = prow * ROWB + ((pchk ^ (prow & 7)) << 4);

  // ---- consumer addressing
  const int wr = (wid >> 2) & 1;           // M half
  const int wc = wid & 3;                  // N quarter
  const int fr = lane & 15;
  const int fq = lane >> 4;
  const int colx0 = ((fq     ^ (fr & 7)) << 4);      // ks=0 granules 0-3
  const int colx1 = (((4 + fq) ^ (fr & 7)) << 4);    // ks=1 granules 4-7
  const int aRow0 = (wr * 128 + fr) * ROWB;
  const int bRow0 = (wc * 64  + fr) * ROWB;

  // ---- prologue: producers stage tile 0 into buffer 0
  if (wid >= 8) {
    stage_tile(aB, bB, 0, smA, smB, pdst0);
    LGKM0();
  }
  BAR();

  if (wid < 8) {
    // ================= consumers =================
    f32x4 acc[8][4];
#pragma unroll
    for (int m = 0; m < 8; ++m)
#pragma unroll
      for (int n = 0; n < 4; ++n) acc[m][n] = (f32x4){0.f, 0.f, 0.f, 0.f};

    for (int t = 0; t < NKT; ++t) {
      char* const cA = smA + (t & 1) * TILE;
      char* const cB = smB + (t & 1) * TILE;
#pragma unroll
      for (int ks = 0; ks < 2; ++ks) {
        const int cx = ks ? colx1 : colx0;
        bf16x8 bfr[4];
#pragma unroll
        for (int n = 0; n < 4; ++n)
          bfr[n] = *(const bf16x8*)(cB + bRow0 + n * 2048 + cx);
        __builtin_amdgcn_s_setprio(1);
#pragma unroll
        for (int m = 0; m < 8; ++m) {
          bf16x8 am = *(const bf16x8*)(cA + aRow0 + m * 2048 + cx);
#pragma unroll
          for (int n = 0; n < 4; ++n)
            acc[m][n] = MFMA_(am, bfr[n], acc[m][n]);
        }
        __builtin_amdgcn_s_setprio(0);
      }
      if (t + 1 < NKT) BAR();
    }

    // ---- epilogue: C/D layout col = lane&15, row = (lane>>4)*4 + reg (m89)
#pragma unroll
    for (int m = 0; m < 8; ++m) {
#pragma unroll
      for (int r = 0; r < 4; ++r) {
        const int row = wr * 128 + m * 16 + fq * 4 + r;
        float* orow = O + ((size_t)(n0 + row) * NG + g) * DOUT + c0 + wc * 64;
#pragma unroll
        for (int n = 0; n < 4; ++n) {
          orow[n * 16 + fr] = acc[m][n][r];
        }
      }
    }
  } else {
    // ================= producers =================
    for (int t = 0; t + 1 < NKT; ++t) {
      char* const nA = smA + ((t + 1) & 1) * TILE;
      char* const nB = smB + ((t + 1) & 1) * TILE;
      stage_tile(aB, bB, (t + 1) * BK, nA, nB, pdst0);
      LGKM0();
      BAR();
    }
  }
}

} // namespace

extern "C" void kernel_launch(void* const* d_in, const int* in_sizes, int n_in,
                              void* d_out, int out_size, void* d_ws, size_t ws_size,
                              hipStream_t stream) {
  (void)n_in; (void)d_ws; (void)ws_size; (void)out_size;
  const float* X = (const float*)d_in[0];
  const float* W = (const float*)d_in[1];
  float* O = (float*)d_out;

  const int tokens_total = in_sizes[0] / DIN;            // 65536
  const int ntok_per_g   = tokens_total / NG;            // 8192
  const int grid = NG * (ntok_per_g / BM) * (DOUT / BN); // 1024

  (void)hipFuncSetAttribute((const void*)gemm_spec,
                            hipFuncAttributeMaxDynamicSharedMemorySize,
                            LDS_BYTES);
  gemm_spec<<<dim3(grid), dim3(768), LDS_BYTES, stream>>>(X, W, O);
}